// Round 9
// baseline (24.022 us; speedup 1.0000x reference)
//
#include <hip/hip_runtime.h>

// CrossConvV2: B=2, n=1024, d=3, f=3, m=26 probes, k=5 convs, o=6 out_feats.
// out[b,l] = [coords(3) | leakyrelu( (wf flat 78 * 10/n) @ W[k] + b[k] ) (30)]
// wf[b,l,m,ff] = sum_nn 1/(|c_nn - c_l - p_m|^2 + 10) * feats[nn,ff]
// |c_nn - c_l - p|^2 + 10 = |d|^2 + 19 - 2 d.p   (|p| = 3 for all probes)
//
// R8: block-granularity probe. R2's profiled run (oversubscribed) showed
// OccupancyPercent 33.8% = ~11 waves/CU = ~2.75 concurrent blocks/CU even
// with 12 queued -> concurrency appears BLOCK-limited, not VGPR/LDS-limited.
// Same 4096 waves as R7 but as 2048 blocks x 128 thr (1 center x 2 waves).
// If blocks/CU is the cap, resident waves double -> busy% up. Plus quad-CSE
// in half1 (u=dy+dz, v=dy-dz: 8->6 ops).

#define NPTS      1024
#define COEFF     10.0f
#define NEG       0.3f

constexpr float PROBE[26][3] = {
  {-2.12132034f,  1.95984445f, -0.81179415f},
  {-2.12132034f,  1.95984445f,  0.81179415f},
  {-2.12132034f,  0.81179415f,  1.95984445f},
  {-2.12132034f, -0.81179415f,  1.95984445f},
  {-2.12132034f, -1.95984445f,  0.81179415f},
  {-2.12132034f, -1.95984445f, -0.81179415f},
  {-2.12132034f, -0.81179415f, -1.95984445f},
  {-2.12132034f,  0.81179415f, -1.95984445f},
  { 0.0f,         3.0f,         0.0f       },
  { 0.0f,         2.12132034f,  2.12132034f},
  { 0.0f,         0.0f,         3.0f       },
  { 0.0f,        -2.12132034f,  2.12132034f},
  { 0.0f,        -3.0f,         0.0f       },
  { 0.0f,        -2.12132034f, -2.12132034f},
  { 0.0f,         0.0f,        -3.0f       },
  { 0.0f,         2.12132034f, -2.12132034f},
  { 2.12132034f,  1.95984445f,  0.81179415f},
  { 2.12132034f,  0.81179415f,  1.95984445f},
  { 2.12132034f, -0.81179415f,  1.95984445f},
  { 2.12132034f, -1.95984445f,  0.81179415f},
  { 2.12132034f, -1.95984445f, -0.81179415f},
  { 2.12132034f, -0.81179415f, -1.95984445f},
  { 2.12132034f,  0.81179415f, -1.95984445f},
  { 2.12132034f,  1.95984445f, -0.81179415f},
  {-3.0f,         0.0f,         0.0f       },
  { 3.0f,         0.0f,         0.0f       },
};

// half0: ring x=-2.121 (8) + y/z-axials (4) + x-axials (2) = 14 probes
// half1: ring x=+2.121 (8) + diagonal quads (4)            = 12 probes
constexpr int H0[14] = {0,1,2,3,4,5,6,7, 8,12,10,14, 24,25};
constexpr int H1[14] = {16,17,18,19,20,21,22,23, 9,11,13,15, 0,0}; // pad

// wave64 sum-reduce via DPP (result valid in lane 63). rocPRIM pattern.
#define DPP_STEP(x, ctrl, rm, bm, bc)                                        \
  x += __int_as_float(__builtin_amdgcn_update_dpp(                           \
      0, __float_as_int(x), ctrl, rm, bm, bc))

__device__ __forceinline__ float wave_sum_to_lane63(float x) {
  DPP_STEP(x, 0x111, 0xf, 0xf, true);   // row_shr:1
  DPP_STEP(x, 0x112, 0xf, 0xf, true);   // row_shr:2
  DPP_STEP(x, 0x114, 0xf, 0xe, false);  // row_shr:4
  DPP_STEP(x, 0x118, 0xf, 0xc, false);  // row_shr:8
  DPP_STEP(x, 0x142, 0xa, 0xf, false);  // row_bcast:15 -> rows 1,3
  DPP_STEP(x, 0x143, 0xc, 0xf, false);  // row_bcast:31 -> rows 2,3
  return x;                              // lane 63 = full sum
}

// t-generation with compile-time zero-skip; shared subtrees CSE via GVN.
// Runs slots 0..J (ring slots only for HALF=1; quads done explicitly).
template <int HALF, int J>
struct TGen {
  static __device__ __forceinline__ void run(float base, float dx, float dy,
                                             float dz, float* t) {
    TGen<HALF, J - 1>::run(base, dx, dy, dz, t);
    constexpr int   m   = HALF ? H1[J] : H0[J];
    constexpr float px2 = -2.0f * PROBE[m][0];
    constexpr float py2 = -2.0f * PROBE[m][1];
    constexpr float pz2 = -2.0f * PROBE[m][2];
    float v = base;                         // x innermost: ring-shared CSE
    if constexpr (px2 != 0.0f) v = fmaf(px2, dx, v);
    if constexpr (py2 != 0.0f) v = fmaf(py2, dy, v);
    if constexpr (pz2 != 0.0f) v = fmaf(pz2, dz, v);
    t[J] = v;
  }
};
template <int HALF>
struct TGen<HALF, -1> {
  static __device__ __forceinline__ void run(float, float, float, float, float*) {}
};

// batched reciprocal: 1 rcp + 9 mul for 4 values (vs 4 rcp)
__device__ __forceinline__ void rcp4(const float* t, float* w) {
  const float p01 = t[0] * t[1], p23 = t[2] * t[3];
  const float r   = __builtin_amdgcn_rcpf(p01 * p23);
  const float r01 = p23 * r, r23 = p01 * r;
  w[0] = t[1] * r01;  w[1] = t[0] * r01;
  w[2] = t[3] * r23;  w[3] = t[2] * r23;
}
__device__ __forceinline__ void rcp2(const float* t, float* w) {
  const float r = __builtin_amdgcn_rcpf(t[0] * t[1]);
  w[0] = t[1] * r;  w[1] = t[0] * r;
}

template <int HALF>
__device__ void run_main(const float* __restrict__ batch,
                         int lane, float cx, float cy, float cz, float* acc) {
  constexpr int NP = HALF ? 12 : 14;
  #pragma unroll 2
  for (int it = 0; it < NPTS / 64; ++it) {
    const float* prow = batch + (it * 64 + lane) * 6;
    const float2 q0 = *reinterpret_cast<const float2*>(prow);
    const float2 q1 = *reinterpret_cast<const float2*>(prow + 2);
    const float2 q2 = *reinterpret_cast<const float2*>(prow + 4);
    const float dx = q0.x - cx, dy = q0.y - cy, dz = q1.x - cz;
    const float f0 = q1.y, f1 = q2.x, f2 = q2.y;
    const float base = fmaf(dx, dx, fmaf(dy, dy, fmaf(dz, dz, 19.0f)));

    float t[NP], w[NP];
    if constexpr (HALF == 0) {
      TGen<0, 13>::run(base, dx, dy, dz, t);
    } else {
      TGen<1, 7>::run(base, dx, dy, dz, t);   // ring16 only
      // diagonal quads via pair-CSE: slots 8..11 = probes 9,11,13,15
      const float u = dy + dz, v = dy - dz;   // 2*2.12132034 = 4.24264068
      t[8]  = fmaf(-4.24264068f, u, base);    // p9  = (0,+2.12,+2.12)
      t[9]  = fmaf( 4.24264068f, v, base);    // p11 = (0,-2.12,+2.12)
      t[10] = fmaf( 4.24264068f, u, base);    // p13 = (0,-2.12,-2.12)
      t[11] = fmaf(-4.24264068f, v, base);    // p15 = (0,+2.12,-2.12)
    }
    rcp4(t + 0, w + 0);
    rcp4(t + 4, w + 4);
    rcp4(t + 8, w + 8);
    if constexpr (NP == 14) rcp2(t + 12, w + 12);

    #pragma unroll
    for (int j = 0; j < NP; ++j) {
      acc[j * 3 + 0] = fmaf(w[j], f0, acc[j * 3 + 0]);
      acc[j * 3 + 1] = fmaf(w[j], f1, acc[j * 3 + 1]);
      acc[j * 3 + 2] = fmaf(w[j], f2, acc[j * 3 + 2]);
    }
  }
}

template <int HALF>
__device__ __forceinline__ void reduce_store(float* acc, int lane, float* sx,
                                             float scale) {
  constexpr int NP = HALF ? 12 : 14;
  #pragma unroll
  for (int j = 0; j < NP * 3; ++j)
    acc[j] = wave_sum_to_lane63(acc[j]) * scale;
  if (lane == 63) {
    #pragma unroll
    for (int j = 0; j < NP; ++j) {
      const int m = HALF ? H1[j] : H0[j];
      sx[m * 3 + 0] = acc[j * 3 + 0];
      sx[m * 3 + 1] = acc[j * 3 + 1];
      sx[m * 3 + 2] = acc[j * 3 + 2];
    }
  }
}

__global__ __launch_bounds__(128, 4) void crossconv_kernel(
    const float* __restrict__ points,  // (2,1024,6)
    const float* __restrict__ W,       // (5,78,6)
    const float* __restrict__ bias,    // (5,6) flat 30
    float* __restrict__ out)           // (2,1024,33)
{
    __shared__ __align__(16) float sx[80];

    const int tid  = threadIdx.x;
    const int lane = tid & 63;
    const int half = tid >> 6;            // wave in block = probe half: 0,1
    const int G    = blockIdx.x;          // global center 0..2047

    const float* batch = points + (G >> 10) * (NPTS * 6);
    const float* crow  = points + G * 6;
    const float  cx = crow[0], cy = crow[1], cz = crow[2];

    float acc[42];
    #pragma unroll
    for (int j = 0; j < 42; ++j) acc[j] = 0.f;

    if (half == 0) run_main<0>(batch, lane, cx, cy, cz, acc);
    else           run_main<1>(batch, lane, cx, cy, cz, acc);

    const float scale = COEFF / (float)NPTS;
    if (half == 0) reduce_store<0>(acc, lane, sx, scale);
    else           reduce_store<1>(acc, lane, sx, scale);
    __syncthreads();

    // tail: wave 0 does the 78->30 matmul + coords for this center
    if (half == 0) {
      float* orow = out + G * 33;
      if (lane < 30) {
        const int k = lane / 6, o = lane % 6;
        const float* Wk = W + k * (78 * 6) + o;  // W[k, t, o], stride 6 over t
        float h0 = bias[lane], h1 = 0.f, h2 = 0.f, h3 = 0.f;
        const float4* sxv = reinterpret_cast<const float4*>(sx);
        #pragma unroll
        for (int t4 = 0; t4 < 19; ++t4) {
          const float4 v = sxv[t4];
          h0 = fmaf(v.x, Wk[(t4 * 4 + 0) * 6], h0);
          h1 = fmaf(v.y, Wk[(t4 * 4 + 1) * 6], h1);
          h2 = fmaf(v.z, Wk[(t4 * 4 + 2) * 6], h2);
          h3 = fmaf(v.w, Wk[(t4 * 4 + 3) * 6], h3);
        }
        const float2 vt = *reinterpret_cast<const float2*>(&sx[76]);
        h0 = fmaf(vt.x, Wk[76 * 6], h0);
        h1 = fmaf(vt.y, Wk[77 * 6], h1);
        float h = (h0 + h2) + (h1 + h3);
        h = (h > 0.f) ? h : NEG * h;
        orow[3 + lane] = h;
      } else if (lane < 33) {
        orow[lane - 30] = (lane == 30) ? cx : ((lane == 31) ? cy : cz);
      }
    }
}

extern "C" void kernel_launch(void* const* d_in, const int* in_sizes, int n_in,
                              void* d_out, int out_size, void* d_ws, size_t ws_size,
                              hipStream_t stream) {
    const float* points = (const float*)d_in[0];  // 2*1024*6
    const float* W      = (const float*)d_in[1];  // 5*78*6
    const float* bias   = (const float*)d_in[2];  // 30
    float* out          = (float*)d_out;          // 2*1024*33
    // 2048 blocks (1 center each) x 2 waves = 4096 waves
    crossconv_kernel<<<2048, 128, 0, stream>>>(points, W, bias, out);
}

// Round 10
// 23.842 us; speedup vs baseline: 1.0075x; 1.0075x over previous
//
#include <hip/hip_runtime.h>

// CrossConvV2: B=2, n=1024, d=3, f=3, m=26 probes, k=5 convs, o=6 out_feats.
// out[b,l] = [coords(3) | leakyrelu( (wf flat 78 * 10/n) @ W[k] + b[k] ) (30)]
// wf[b,l,m,ff] = sum_nn 1/(|c_nn - c_l - p_m|^2 + 10) * feats[nn,ff]
// |c_nn - c_l - p|^2 + 10 = |d|^2 + 19 - 2 d.p   (|p| = 3 for all probes)
//
// R9: VOP3P packed fp32. Only measured lever so far = VALU issue count
// (marginal ~0.45ns/cyc/SIMD). Pack with v_pk_fma_f32/v_pk_mul_f32 via
// ext_vector float2:
//  - ring probes pair (+y,-y | same x,z): both t's in one pk_fma
//  - batched-rcp recovery muls packed
//  - acc: features (f0,f1) as v2f -> pk_fma + scalar fma for f2
//  - scale folded into tail (h = dot*scale + bias)

#define NPTS   1024
#define COEFF  10.0f
#define NEG    0.3f

typedef float v2f __attribute__((ext_vector_type(2)));

__device__ __forceinline__ v2f pkfma(v2f a, v2f b, v2f c) {
#if __has_builtin(__builtin_elementwise_fma)
  return __builtin_elementwise_fma(a, b, c);
#else
  return v2f{fmaf(a.x, b.x, c.x), fmaf(a.y, b.y, c.y)};
#endif
}
__device__ __forceinline__ v2f splat(float s) { return v2f{s, s}; }

// slot -> probe index (for sx store); pairs are (2p, 2p+1)
constexpr int M0[14] = {0,5, 1,4, 2,3, 7,6, 8,12, 10,14, 24,25};
constexpr int M1[12] = {16,19, 17,18, 20,23, 21,22, 9,13, 11,15};

// wave64 sum-reduce via DPP (result valid in lane 63). rocPRIM pattern.
#define DPP_STEP(x, ctrl, rm, bm, bc)                                        \
  x += __int_as_float(__builtin_amdgcn_update_dpp(                           \
      0, __float_as_int(x), ctrl, rm, bm, bc))

__device__ __forceinline__ float wave_sum_to_lane63(float x) {
  DPP_STEP(x, 0x111, 0xf, 0xf, true);   // row_shr:1
  DPP_STEP(x, 0x112, 0xf, 0xf, true);   // row_shr:2
  DPP_STEP(x, 0x114, 0xf, 0xe, false);  // row_shr:4
  DPP_STEP(x, 0x118, 0xf, 0xc, false);  // row_shr:8
  DPP_STEP(x, 0x142, 0xa, 0xf, false);  // row_bcast:15 -> rows 1,3
  DPP_STEP(x, 0x143, 0xc, 0xf, false);  // row_bcast:31 -> rows 2,3
  return x;                              // lane 63 = full sum
}

// batched reciprocal over two t-pairs: 1 rcp, packed recovery muls
__device__ __forceinline__ void rcp4pk(v2f tA, v2f tB, v2f& wA, v2f& wB) {
  const float pA = tA.x * tA.y;
  const float pB = tB.x * tB.y;
  const float r  = __builtin_amdgcn_rcpf(pA * pB);
  const v2f  rp  = v2f{pB, pA} * r;          // {1/pA, 1/pB}
  wA = v2f{tA.y, tA.x} * rp.x;               // {1/t0, 1/t1}
  wB = v2f{tB.y, tB.x} * rp.y;
}
__device__ __forceinline__ v2f rcp2pk(v2f t) {
  const float r = __builtin_amdgcn_rcpf(t.x * t.y);
  return v2f{t.y, t.x} * r;
}

// 2*probe coordinate magnitudes
#define CA 4.24264068f   // 2*2.12132034
#define CY 3.91968890f   // 2*1.95984445
#define CZ 1.62358830f   // 2*0.81179415

template <int HALF>
__device__ void run_main(const float* __restrict__ batch, int lane,
                         float cx, float cy, float cz, v2f* a01, float* a2) {
  constexpr int NPAIR = HALF ? 6 : 7;
  #pragma unroll 2
  for (int it = 0; it < NPTS / 64; ++it) {
    const float* prow = batch + (it * 64 + lane) * 6;
    const float2 q0 = *reinterpret_cast<const float2*>(prow);
    const float2 q1 = *reinterpret_cast<const float2*>(prow + 2);
    const float2 q2 = *reinterpret_cast<const float2*>(prow + 4);
    const float dx = q0.x - cx, dy = q0.y - cy, dz = q1.x - cz;
    const v2f   f01 = {q1.y, q2.x};
    const float f2  = q2.y;
    const float base = fmaf(dx, dx, fmaf(dy, dy, fmaf(dz, dz, 19.0f)));

    v2f tp[7];
    if constexpr (HALF == 0) {
      // ring x=-2.1213 (px2=+CA), pairs (+y,-y) share z-term
      const float rx = fmaf(CA, dx, base);
      const float sA = fmaf( CZ, dz, rx);   // z=-0.81: (p0,p5)
      const float sB = fmaf(-CZ, dz, rx);   // z=+0.81: (p1,p4)
      const float sC = fmaf(-CY, dz, rx);   // z=+1.96: (p2,p3)
      const float sD = fmaf( CY, dz, rx);   // z=-1.96: (p7,p6)
      tp[0] = pkfma(v2f{-CY,  CY}, splat(dy), splat(sA));
      tp[1] = pkfma(v2f{-CY,  CY}, splat(dy), splat(sB));
      tp[2] = pkfma(v2f{-CZ,  CZ}, splat(dy), splat(sC));
      tp[3] = pkfma(v2f{-CZ,  CZ}, splat(dy), splat(sD));
      tp[4] = pkfma(v2f{-6.f, 6.f}, splat(dy), splat(base));  // p8,p12
      tp[5] = pkfma(v2f{-6.f, 6.f}, splat(dz), splat(base));  // p10,p14
      tp[6] = pkfma(v2f{ 6.f,-6.f}, splat(dx), splat(base));  // p24,p25
    } else {
      // ring x=+2.1213 (px2=-CA)
      const float rx = fmaf(-CA, dx, base);
      const float sA = fmaf(-CZ, dz, rx);   // z=+0.81: (p16,p19)
      const float sB = fmaf(-CY, dz, rx);   // z=+1.96: (p17,p18)
      const float sC = fmaf( CZ, dz, rx);   // z=-0.81: (p20,p23)
      const float sD = fmaf( CY, dz, rx);   // z=-1.96: (p21,p22)
      tp[0] = pkfma(v2f{-CY,  CY}, splat(dy), splat(sA));
      tp[1] = pkfma(v2f{-CZ,  CZ}, splat(dy), splat(sB));
      tp[2] = pkfma(v2f{ CY, -CY}, splat(dy), splat(sC));
      tp[3] = pkfma(v2f{ CZ, -CZ}, splat(dy), splat(sD));
      const float u = dy + dz, v = dy - dz; // diagonal quads
      tp[4] = pkfma(v2f{-CA,  CA}, splat(u), splat(base));    // p9,p13
      tp[5] = pkfma(v2f{ CA, -CA}, splat(v), splat(base));    // p11,p15
    }

    v2f wp[7];
    rcp4pk(tp[0], tp[1], wp[0], wp[1]);
    rcp4pk(tp[2], tp[3], wp[2], wp[3]);
    rcp4pk(tp[4], tp[5], wp[4], wp[5]);
    if constexpr (HALF == 0) wp[6] = rcp2pk(tp[6]);

    #pragma unroll
    for (int p = 0; p < NPAIR; ++p) {
      a01[2*p]     = pkfma(splat(wp[p].x), f01, a01[2*p]);
      a01[2*p + 1] = pkfma(splat(wp[p].y), f01, a01[2*p + 1]);
      a2[2*p]      = fmaf(wp[p].x, f2, a2[2*p]);
      a2[2*p + 1]  = fmaf(wp[p].y, f2, a2[2*p + 1]);
    }
  }
}

template <int HALF>
__device__ __forceinline__ void reduce_store(v2f* a01, float* a2, int lane,
                                             float* sx) {
  constexpr int NP = HALF ? 12 : 14;
  #pragma unroll
  for (int j = 0; j < NP; ++j) {
    a01[j].x = wave_sum_to_lane63(a01[j].x);
    a01[j].y = wave_sum_to_lane63(a01[j].y);
    a2[j]    = wave_sum_to_lane63(a2[j]);
  }
  if (lane == 63) {
    #pragma unroll
    for (int j = 0; j < NP; ++j) {
      const int m = HALF ? M1[j] : M0[j];
      sx[m * 3 + 0] = a01[j].x;
      sx[m * 3 + 1] = a01[j].y;
      sx[m * 3 + 2] = a2[j];
    }
  }
}

__global__ __launch_bounds__(256, 4) void crossconv_kernel(
    const float* __restrict__ points,  // (2,1024,6)
    const float* __restrict__ W,       // (5,78,6)
    const float* __restrict__ bias,    // (5,6) flat 30
    float* __restrict__ out)           // (2,1024,33)
{
    __shared__ __align__(16) float sx[2][80];

    const int tid    = threadIdx.x;
    const int lane   = tid & 63;
    const int w      = tid >> 6;          // wave in block: 0..3
    const int cLocal = w >> 1;            // center within block: 0,1
    const int half   = w & 1;             // probe half: 0,1
    const int G      = blockIdx.x * 2 + cLocal;   // global center 0..2047

    const float* batch = points + (G >> 10) * (NPTS * 6);
    const float* crow  = points + G * 6;
    const float  cx = crow[0], cy = crow[1], cz = crow[2];

    v2f   a01[14];
    float a2[14];
    #pragma unroll
    for (int j = 0; j < 14; ++j) { a01[j] = v2f{0.f, 0.f}; a2[j] = 0.f; }

    if (half == 0) run_main<0>(batch, lane, cx, cy, cz, a01, a2);
    else           run_main<1>(batch, lane, cx, cy, cz, a01, a2);

    if (half == 0) reduce_store<0>(a01, a2, lane, sx[cLocal]);
    else           reduce_store<1>(a01, a2, lane, sx[cLocal]);
    __syncthreads();

    // tail: waves with half==0 do the 78->30 matmul + coords for their center
    if (half == 0) {
      const float scale = COEFF / (float)NPTS;   // folded here, not in reduce
      float* orow = out + G * 33;
      if (lane < 30) {
        const int k = lane / 6, o = lane % 6;
        const float* Wk = W + k * (78 * 6) + o;  // W[k, t, o], stride 6 over t
        float h0 = 0.f, h1 = 0.f, h2 = 0.f, h3 = 0.f;
        const float4* sxv = reinterpret_cast<const float4*>(sx[cLocal]);
        #pragma unroll
        for (int t4 = 0; t4 < 19; ++t4) {
          const float4 v = sxv[t4];
          h0 = fmaf(v.x, Wk[(t4 * 4 + 0) * 6], h0);
          h1 = fmaf(v.y, Wk[(t4 * 4 + 1) * 6], h1);
          h2 = fmaf(v.z, Wk[(t4 * 4 + 2) * 6], h2);
          h3 = fmaf(v.w, Wk[(t4 * 4 + 3) * 6], h3);
        }
        const float2 vt = *reinterpret_cast<const float2*>(&sx[cLocal][76]);
        h0 = fmaf(vt.x, Wk[76 * 6], h0);
        h1 = fmaf(vt.y, Wk[77 * 6], h1);
        const float dot = (h0 + h2) + (h1 + h3);
        float h = fmaf(dot, scale, bias[lane]);
        h = (h > 0.f) ? h : NEG * h;
        orow[3 + lane] = h;
      } else if (lane < 33) {
        orow[lane - 30] = (lane == 30) ? cx : ((lane == 31) ? cy : cz);
      }
    }
}

extern "C" void kernel_launch(void* const* d_in, const int* in_sizes, int n_in,
                              void* d_out, int out_size, void* d_ws, size_t ws_size,
                              hipStream_t stream) {
    const float* points = (const float*)d_in[0];  // 2*1024*6
    const float* W      = (const float*)d_in[1];  // 5*78*6
    const float* bias   = (const float*)d_in[2];  // 30
    float* out          = (float*)d_out;          // 2*1024*33
    // 1024 blocks x 4 waves = 2048 centers x 2 probe-halves
    crossconv_kernel<<<1024, 256, 0, stream>>>(points, W, bias, out);
}

// Round 13
// 23.692 us; speedup vs baseline: 1.0139x; 1.0063x over previous
//
#include <hip/hip_runtime.h>

// CrossConvV2: B=2, n=1024, d=3, f=3, m=26 probes, k=5 convs, o=6 out_feats.
// out[b,l] = [coords(3) | leakyrelu( (wf flat 78 * 10/n) @ W[k] + b[k] ) (30)]
// wf[b,l,m,ff] = sum_nn 1/(|c_nn - c_l - p_m|^2 + 10) * feats[nn,ff]
// |c_nn - c_l - p|^2 + 10 = |d|^2 + 19 - 2 d.p   (|p| = 3 for all probes)
//
// R12: NEIGHBOR-pair packing (R11's probe-pair pk asm needs VGPR-pair
// operands -> dead end). Two neighbors A,B per lane-step:
//  - d, base, t as v2f over {A,B} (elementwise C -> pk ops if compiler wills)
//  - rcp2 per probe across the pair: 4 insts / 2 values (trans-safe)
//  - w packed via cvt_pkrtz(wA,wB) -> v_dot2_f32_f16 accumulate (42 vs 84)
// Scalar CSE structure identical to R9 (validated, absmax 1.2e-4).

#define NPTS   1024
#define COEFF  10.0f
#define NEG    0.3f

typedef float  v2f __attribute__((ext_vector_type(2)));
typedef __fp16 h2  __attribute__((ext_vector_type(2)));

#define CA 4.24264068f   // 2*2.12132034
#define CY 3.91968890f   // 2*1.95984445
#define CZ 1.62358830f   // 2*0.81179415

// slot -> probe index (R9-validated mapping)
constexpr int M0[14] = {0,5, 1,4, 2,3, 7,6, 8,12, 10,14, 24,25};
constexpr int M1[12] = {16,19, 17,18, 20,23, 21,22, 9,13, 11,15};

__device__ __forceinline__ v2f vfma(float c, v2f a, v2f b) {
#if __has_builtin(__builtin_elementwise_fma)
  return __builtin_elementwise_fma(v2f{c, c}, a, b);
#else
  return v2f{fmaf(c, a.x, b.x), fmaf(c, a.y, b.y)};
#endif
}

// wave64 sum-reduce via DPP (result valid in lane 63). rocPRIM pattern.
#define DPP_STEP(x, ctrl, rm, bm, bc)                                        \
  x += __int_as_float(__builtin_amdgcn_update_dpp(                           \
      0, __float_as_int(x), ctrl, rm, bm, bc))

__device__ __forceinline__ float wave_sum_to_lane63(float x) {
  DPP_STEP(x, 0x111, 0xf, 0xf, true);   // row_shr:1
  DPP_STEP(x, 0x112, 0xf, 0xf, true);   // row_shr:2
  DPP_STEP(x, 0x114, 0xf, 0xe, false);  // row_shr:4
  DPP_STEP(x, 0x118, 0xf, 0xc, false);  // row_shr:8
  DPP_STEP(x, 0x142, 0xa, 0xf, false);  // row_bcast:15 -> rows 1,3
  DPP_STEP(x, 0x143, 0xc, 0xf, false);  // row_bcast:31 -> rows 2,3
  return x;                              // lane 63 = full sum
}

// t-slot generation, v2f over the neighbor pair. R9's CSE structure.
template <int HALF>
__device__ __forceinline__ void tgen(v2f dx, v2f dy, v2f dz, v2f base, v2f* t) {
  if constexpr (HALF == 0) {
    const v2f rx = vfma( CA, dx, base);   // ring x=-2.1213
    const v2f sA = vfma( CZ, dz, rx);
    const v2f sB = vfma(-CZ, dz, rx);
    const v2f sC = vfma(-CY, dz, rx);
    const v2f sD = vfma( CY, dz, rx);
    t[0]  = vfma(-CY, dy, sA);   t[1]  = vfma( CY, dy, sA);   // p0,p5
    t[2]  = vfma(-CY, dy, sB);   t[3]  = vfma( CY, dy, sB);   // p1,p4
    t[4]  = vfma(-CZ, dy, sC);   t[5]  = vfma( CZ, dy, sC);   // p2,p3
    t[6]  = vfma(-CZ, dy, sD);   t[7]  = vfma( CZ, dy, sD);   // p7,p6
    t[8]  = vfma(-6.f, dy, base); t[9]  = vfma( 6.f, dy, base); // p8,p12
    t[10] = vfma(-6.f, dz, base); t[11] = vfma( 6.f, dz, base); // p10,p14
    t[12] = vfma( 6.f, dx, base); t[13] = vfma(-6.f, dx, base); // p24,p25
  } else {
    const v2f rx = vfma(-CA, dx, base);   // ring x=+2.1213
    const v2f sA = vfma(-CZ, dz, rx);
    const v2f sB = vfma(-CY, dz, rx);
    const v2f sC = vfma( CZ, dz, rx);
    const v2f sD = vfma( CY, dz, rx);
    const v2f u = dy + dz, v = dy - dz;
    t[0]  = vfma(-CY, dy, sA);   t[1]  = vfma( CY, dy, sA);   // p16,p19
    t[2]  = vfma(-CZ, dy, sB);   t[3]  = vfma( CZ, dy, sB);   // p17,p18
    t[4]  = vfma( CY, dy, sC);   t[5]  = vfma(-CY, dy, sC);   // p20,p23
    t[6]  = vfma( CZ, dy, sD);   t[7]  = vfma(-CZ, dy, sD);   // p21,p22
    t[8]  = vfma(-CA, u, base);  t[9]  = vfma( CA, u, base);  // p9,p13
    t[10] = vfma( CA, v, base);  t[11] = vfma(-CA, v, base);  // p11,p15
  }
}

template <int HALF>
__device__ void run_main(const float* __restrict__ batch, int lane,
                         float cx, float cy, float cz, float* acc) {
  constexpr int NP = HALF ? 12 : 14;
  for (int it = 0; it < NPTS / 128; ++it) {    // neighbors A,B per step
    const float* prowA = batch + (it * 128 + lane) * 6;
    const float* prowB = prowA + 64 * 6;
    const float2 a0 = *reinterpret_cast<const float2*>(prowA);
    const float2 a1 = *reinterpret_cast<const float2*>(prowA + 2);
    const float2 a2 = *reinterpret_cast<const float2*>(prowA + 4);
    const float2 b0 = *reinterpret_cast<const float2*>(prowB);
    const float2 b1 = *reinterpret_cast<const float2*>(prowB + 2);
    const float2 b2 = *reinterpret_cast<const float2*>(prowB + 4);

    const v2f dx = v2f{a0.x, b0.x} - cx;
    const v2f dy = v2f{a0.y, b0.y} - cy;
    const v2f dz = v2f{a1.x, b1.x} - cz;
    v2f base = vfma(1.f, dz * dz, v2f{19.f, 19.f});
    base = __builtin_elementwise_fma(dy, dy, base);
    base = __builtin_elementwise_fma(dx, dx, base);

    v2f t[NP];
    tgen<HALF>(dx, dy, dz, base, t);

    // f16-packed features across the pair
    const h2 f0p = __builtin_amdgcn_cvt_pkrtz(a1.y, b1.y);
    const h2 f1p = __builtin_amdgcn_cvt_pkrtz(a2.x, b2.x);
    const h2 f2p = __builtin_amdgcn_cvt_pkrtz(a2.y, b2.y);

    #pragma unroll
    for (int j = 0; j < NP; ++j) {
      // rcp2 across the neighbor pair: w = {1/tA, 1/tB}
      const float r  = __builtin_amdgcn_rcpf(t[j].x * t[j].y);
      const h2 wp = __builtin_amdgcn_cvt_pkrtz(t[j].y * r, t[j].x * r);
      acc[j * 3 + 0] = __builtin_amdgcn_fdot2(wp, f0p, acc[j * 3 + 0], false);
      acc[j * 3 + 1] = __builtin_amdgcn_fdot2(wp, f1p, acc[j * 3 + 1], false);
      acc[j * 3 + 2] = __builtin_amdgcn_fdot2(wp, f2p, acc[j * 3 + 2], false);
    }
  }
}

template <int HALF>
__device__ __forceinline__ void reduce_store(float* acc, int lane, float* sx) {
  constexpr int NP = HALF ? 12 : 14;
  #pragma unroll
  for (int j = 0; j < NP * 3; ++j)
    acc[j] = wave_sum_to_lane63(acc[j]);
  if (lane == 63) {
    #pragma unroll
    for (int j = 0; j < NP; ++j) {
      const int m = HALF ? M1[j] : M0[j];
      sx[m * 3 + 0] = acc[j * 3 + 0];
      sx[m * 3 + 1] = acc[j * 3 + 1];
      sx[m * 3 + 2] = acc[j * 3 + 2];
    }
  }
}

__global__ __launch_bounds__(256, 4) void crossconv_kernel(
    const float* __restrict__ points,  // (2,1024,6)
    const float* __restrict__ W,       // (5,78,6)
    const float* __restrict__ bias,    // (5,6) flat 30
    float* __restrict__ out)           // (2,1024,33)
{
    __shared__ __align__(16) float sx[2][80];

    const int tid    = threadIdx.x;
    const int lane   = tid & 63;
    const int w      = tid >> 6;          // wave in block: 0..3
    const int cLocal = w >> 1;            // center within block: 0,1
    const int half   = w & 1;             // probe half: 0,1
    const int G      = blockIdx.x * 2 + cLocal;   // global center 0..2047

    const float* batch = points + (G >> 10) * (NPTS * 6);
    const float* crow  = points + G * 6;
    const float  cx = crow[0], cy = crow[1], cz = crow[2];

    float acc[42];
    #pragma unroll
    for (int j = 0; j < 42; ++j) acc[j] = 0.f;

    if (half == 0) run_main<0>(batch, lane, cx, cy, cz, acc);
    else           run_main<1>(batch, lane, cx, cy, cz, acc);

    if (half == 0) reduce_store<0>(acc, lane, sx[cLocal]);
    else           reduce_store<1>(acc, lane, sx[cLocal]);
    __syncthreads();

    // tail: waves with half==0 do the 78->30 matmul + coords for their center
    if (half == 0) {
      const float scale = COEFF / (float)NPTS;   // folded here
      float* orow = out + G * 33;
      if (lane < 30) {
        const int k = lane / 6, o = lane % 6;
        const float* Wk = W + k * (78 * 6) + o;  // W[k, t, o], stride 6 over t
        float h0 = 0.f, h1 = 0.f, h2_ = 0.f, h3 = 0.f;
        const float4* sxv = reinterpret_cast<const float4*>(sx[cLocal]);
        #pragma unroll
        for (int t4 = 0; t4 < 19; ++t4) {
          const float4 v = sxv[t4];
          h0  = fmaf(v.x, Wk[(t4 * 4 + 0) * 6], h0);
          h1  = fmaf(v.y, Wk[(t4 * 4 + 1) * 6], h1);
          h2_ = fmaf(v.z, Wk[(t4 * 4 + 2) * 6], h2_);
          h3  = fmaf(v.w, Wk[(t4 * 4 + 3) * 6], h3);
        }
        const float2 vt = *reinterpret_cast<const float2*>(&sx[cLocal][76]);
        h0 = fmaf(vt.x, Wk[76 * 6], h0);
        h1 = fmaf(vt.y, Wk[77 * 6], h1);
        const float dot = (h0 + h2_) + (h1 + h3);
        float h = fmaf(dot, scale, bias[lane]);
        h = (h > 0.f) ? h : NEG * h;
        orow[3 + lane] = h;
      } else if (lane < 33) {
        orow[lane - 30] = (lane == 30) ? cx : ((lane == 31) ? cy : cz);
      }
    }
}

extern "C" void kernel_launch(void* const* d_in, const int* in_sizes, int n_in,
                              void* d_out, int out_size, void* d_ws, size_t ws_size,
                              hipStream_t stream) {
    const float* points = (const float*)d_in[0];  // 2*1024*6
    const float* W      = (const float*)d_in[1];  // 5*78*6
    const float* bias   = (const float*)d_in[2];  // 30
    float* out          = (float*)d_out;          // 2*1024*33
    // 1024 blocks x 4 waves = 2048 centers x 2 probe-halves
    crossconv_kernel<<<1024, 256, 0, stream>>>(points, W, bias, out);
}